// Round 4
// baseline (1309.276 us; speedup 1.0000x reference)
//
#include <hip/hip_runtime.h>

#define B 16384
#define ENC_LEN 48
#define ENC_HID 128
#define T_DEC 12

__device__ __forceinline__ float fast_rcp(float x) { return __builtin_amdgcn_rcpf(x); }
__device__ __forceinline__ float fast_exp(float x) { return __expf(x); }
__device__ __forceinline__ float sigmoidf_(float x) { return fast_rcp(1.f + fast_exp(-x)); }
__device__ __forceinline__ float tanhf_(float x) {
    // 1 - 2/(e^{2x}+1); correct saturation for |x| large
    return 1.f - 2.f * fast_rcp(1.f + fast_exp(2.f * x));
}
__device__ __forceinline__ float nan_to_num_(float v) { return (v != v) ? 0.f : v; }
__device__ __forceinline__ float dot4(float4 a, const float* v) {
    return a.x * v[0] + a.y * v[1] + a.z * v[2] + a.w * v[3];
}

// ---------------- precompute P (unchanged; at its HBM roofline ~70us) ----------------
// P[e*B + b] = float4( enc_row(e,b) . comb_W[i, 0:128] ), i = 0..3
__global__ __launch_bounds__(256) void precompute_P_kernel(
    const float* __restrict__ enc,    // (48, B, 128) f32
    const float* __restrict__ cW,     // (4, 132) f32
    float4* __restrict__ P)
{
    const int l = threadIdx.x & 7;
    const int rowLocal = threadIdx.x >> 3;

    float w[4][4][4];
    #pragma unroll
    for (int i = 0; i < 4; ++i)
        #pragma unroll
        for (int k = 0; k < 4; ++k) {
            float4 t = *(const float4*)(cW + i * 132 + k * 32 + l * 4);
            w[i][k][0] = t.x; w[i][k][1] = t.y; w[i][k][2] = t.z; w[i][k][3] = t.w;
        }

    const int totalRows = ENC_LEN * B;
    const int stride = gridDim.x * 32;
    for (int row = blockIdx.x * 32 + rowLocal; row < totalRows; row += stride) {
        const float* r = enc + (size_t)row * ENC_HID;
        float4 e[4];
        #pragma unroll
        for (int k = 0; k < 4; ++k)
            e[k] = *(const float4*)(r + k * 32 + l * 4);

        float a[4];
        #pragma unroll
        for (int i = 0; i < 4; ++i) {
            float s0 = e[0].x * w[i][0][0] + e[0].y * w[i][0][1] + e[0].z * w[i][0][2] + e[0].w * w[i][0][3];
            float s1 = e[1].x * w[i][1][0] + e[1].y * w[i][1][1] + e[1].z * w[i][1][2] + e[1].w * w[i][1][3];
            float s2 = e[2].x * w[i][2][0] + e[2].y * w[i][2][1] + e[2].z * w[i][2][2] + e[2].w * w[i][2][3];
            float s3 = e[3].x * w[i][3][0] + e[3].y * w[i][3][1] + e[3].z * w[i][3][2] + e[3].w * w[i][3][3];
            a[i] = (s0 + s1) + (s2 + s3);
        }
        #pragma unroll
        for (int m = 1; m < 8; m <<= 1) {
            #pragma unroll
            for (int i = 0; i < 4; ++i)
                a[i] += __shfl_xor(a[i], m, 8);
        }
        if (l == 0) P[row] = make_float4(a[0], a[1], a[2], a[3]);
    }
}

// ---------------- cooperative decode, 4 blocks/CU ----------------
// Block: 256 threads = 4 waves, 16 batch elements. b = lane&15.
// Worker sub = wave*4 + (lane>>4) in [0,16): owns enc positions {3sub..3sub+2}
// and GRU units {2sub, 2sub+1}. Grid = B/16 = 1024 blocks -> 4 blocks/CU so
// barrier stalls of one block are covered by the other three. Weight loads are
// 4-way divergent vector loads; the ~24 KB weight set is shared by all 4
// blocks and L1-resident after step 0. Reductions: shfl_xor(16,32) within
// wave, then one LDS atomicAdd per wave into a parity-double-buffered array.
__global__ __launch_bounds__(256, 4) void decode_kernel(
    const float* __restrict__ y,        // (B,13,4)
    const float* __restrict__ hidden,   // (B,32)
    const float4* __restrict__ P,       // (48,B) f32x4
    const float* __restrict__ aW,       // (48,36)
    const float* __restrict__ ab,       // (48)
    const float* __restrict__ cW,       // (4,132)
    const float* __restrict__ cb,       // (4)
    const float* __restrict__ wih,      // (96,4)
    const float* __restrict__ whh,      // (96,32)
    const float* __restrict__ bih,      // (96)
    const float* __restrict__ bhh,      // (96)
    const float* __restrict__ fW,       // (32)
    const float* __restrict__ fb,       // (1)
    float* __restrict__ out)            // (12,B)
{
    __shared__ float sh_h[16][36];      // h[b][0:32], stride 36 (2-way banks: free)
    __shared__ float sh_red[2][16][8];  // per-b: S, cc0..3, o_partial

    const int tid  = threadIdx.x;
    const int lane = tid & 63;
    const int bl   = lane & 15;                // local batch index
    const int sub  = (tid >> 6) * 4 + (lane >> 4);  // worker 0..15
    const int gb   = blockIdx.x * 16 + bl;     // global batch index
    const int g0   = sub * 2;                  // first GRU unit owned

    // stage hidden: worker writes its own two units
    {
        float2 v = *(const float2*)(hidden + (size_t)gb * 32 + g0);
        *(float2*)(&sh_h[bl][g0]) = v;
    }
    // zero both reduction buffers (2*16*8 = 256 floats, one per thread)
    (&sh_red[0][0][0])[tid] = 0.f;

    // preload this worker's P fragments (t-invariant)
    float4 pb[3];
    #pragma unroll
    for (int i = 0; i < 3; ++i)
        pb[i] = P[(size_t)(sub * 3 + i) * B + gb];

    float xA[4];
    {
        float4 yv = *(const float4*)(y + (size_t)gb * 52);
        xA[0] = nan_to_num_(yv.x); xA[1] = nan_to_num_(yv.y);
        xA[2] = nan_to_num_(yv.z); xA[3] = nan_to_num_(yv.w);
    }

    __syncthreads();

    for (int t = 0; t < T_DEC; ++t) {
        const int buf = t & 1;

        // ---- A: full h -> registers (8x ds_read_b128, broadcast across dup lanes) ----
        float h[32];
        #pragma unroll
        for (int k = 0; k < 8; ++k) {
            float4 v = *(const float4*)(&sh_h[bl][k * 4]);
            h[4 * k + 0] = v.x; h[4 * k + 1] = v.y; h[4 * k + 2] = v.z; h[4 * k + 3] = v.w;
        }

        // ---- B: this worker's 3 attention logits + softmax partials ----
        float Sp = 0.f, c0 = 0.f, c1 = 0.f, c2 = 0.f, c3 = 0.f;
        #pragma unroll
        for (int i = 0; i < 3; ++i) {
            const int e = sub * 3 + i;
            const float4* wr = (const float4*)(aW + e * 36);   // 144B-aligned
            float s = ab[e] + dot4(wr[0], xA);
            #pragma unroll
            for (int q = 0; q < 8; ++q)
                s += dot4(wr[1 + q], h + 4 * q);
            float g = fast_exp(s);
            Sp += g;
            c0 += g * pb[i].x; c1 += g * pb[i].y; c2 += g * pb[i].z; c3 += g * pb[i].w;
        }
        // reduce the 4 workers of this wave (lanes b, b+16, b+32, b+48)
        #pragma unroll
        for (int m = 16; m < 64; m <<= 1) {
            Sp += __shfl_xor(Sp, m);
            c0 += __shfl_xor(c0, m); c1 += __shfl_xor(c1, m);
            c2 += __shfl_xor(c2, m); c3 += __shfl_xor(c3, m);
        }
        if (lane < 16) {   // one adder per wave per b; 4-way contention across waves
            atomicAdd(&sh_red[buf][bl][0], Sp);
            atomicAdd(&sh_red[buf][bl][1], c0);
            atomicAdd(&sh_red[buf][bl][2], c1);
            atomicAdd(&sh_red[buf][bl][3], c2);
            atomicAdd(&sh_red[buf][bl][4], c3);
        }

        __syncthreads();   // softmax partials complete

        // ---- C: x2 (replicated per worker), zero other buffer ----
        const float rs = fast_rcp(sh_red[buf][bl][0]);
        float x2v[4];
        #pragma unroll
        for (int i = 0; i < 4; ++i) {
            const float* cr = cW + i * 132 + 128;   // uniform -> SGPR
            x2v[i] = sh_red[buf][bl][1 + i] * rs
                   + cr[0] * xA[0] + cr[1] * xA[1] + cr[2] * xA[2] + cr[3] * xA[3] + cb[i];
        }
        if (tid < 128) {   // zero buf^1 for step t+1 (its readers all pre-date barrier above)
            (&sh_red[buf ^ 1][0][0])[tid] = 0.f;
        }

        // ---- D: GRU for units g0, g0+1 ----
        float2 bir = *(const float2*)(bih + g0);
        float2 biz = *(const float2*)(bih + 32 + g0);
        float2 bin = *(const float2*)(bih + 64 + g0);
        float ir0 = bir.x + dot4(*(const float4*)(wih + (g0)      * 4), x2v);
        float ir1 = bir.y + dot4(*(const float4*)(wih + (g0 + 1)  * 4), x2v);
        float iz0 = biz.x + dot4(*(const float4*)(wih + (g0 + 32) * 4), x2v);
        float iz1 = biz.y + dot4(*(const float4*)(wih + (g0 + 33) * 4), x2v);
        float in0 = bin.x + dot4(*(const float4*)(wih + (g0 + 64) * 4), x2v);
        float in1 = bin.y + dot4(*(const float4*)(wih + (g0 + 65) * 4), x2v);

        float2 bhr = *(const float2*)(bhh + g0);
        float2 bhz = *(const float2*)(bhh + 32 + g0);
        float2 bhn = *(const float2*)(bhh + 64 + g0);
        float hr0 = bhr.x, hr1 = bhr.y, hz0 = bhz.x, hz1 = bhz.y, hn0 = bhn.x, hn1 = bhn.y;
        const float* w0 = whh + (size_t)(g0)      * 32;
        const float* w1 = whh + (size_t)(g0 + 1)  * 32;
        const float* w2 = whh + (size_t)(g0 + 32) * 32;
        const float* w3 = whh + (size_t)(g0 + 33) * 32;
        const float* w4 = whh + (size_t)(g0 + 64) * 32;
        const float* w5 = whh + (size_t)(g0 + 65) * 32;
        #pragma unroll
        for (int q = 0; q < 8; ++q) {
            const float* hq = h + 4 * q;
            hr0 += dot4(*(const float4*)(w0 + 4 * q), hq);
            hr1 += dot4(*(const float4*)(w1 + 4 * q), hq);
            hz0 += dot4(*(const float4*)(w2 + 4 * q), hq);
            hz1 += dot4(*(const float4*)(w3 + 4 * q), hq);
            hn0 += dot4(*(const float4*)(w4 + 4 * q), hq);
            hn1 += dot4(*(const float4*)(w5 + 4 * q), hq);
        }
        float r0 = sigmoidf_(ir0 + hr0), r1 = sigmoidf_(ir1 + hr1);
        float z0 = sigmoidf_(iz0 + hz0), z1 = sigmoidf_(iz1 + hz1);
        float n0 = tanhf_(in0 + r0 * hn0), n1 = tanhf_(in1 + r1 * hn1);
        float hw0 = (1.f - z0) * n0 + z0 * h[g0];
        float hw1 = (1.f - z1) * n1 + z1 * h[g0 + 1];
        *(float2*)(&sh_h[bl][g0]) = make_float2(hw0, hw1);

        float fcp = fW[g0] * hw0 + fW[g0 + 1] * hw1;
        #pragma unroll
        for (int m = 16; m < 64; m <<= 1) fcp += __shfl_xor(fcp, m);
        if (lane < 16) atomicAdd(&sh_red[buf][bl][5], fcp);

        __syncthreads();   // h written, fc reduced

        // ---- E: output + next x (o needed by every worker) ----
        const float o = sh_red[buf][bl][5] + fb[0];
        if (tid < 16) out[t * B + gb] = o;

        if (t < T_DEC - 1) {
            float4 yv = *(const float4*)(y + (size_t)gb * 52 + (t + 1) * 4);
            xA[0] = yv.y; xA[1] = yv.z; xA[2] = yv.w; xA[3] = o;
        }
    }
}

extern "C" void kernel_launch(void* const* d_in, const int* in_sizes, int n_in,
                              void* d_out, int out_size, void* d_ws, size_t ws_size,
                              hipStream_t stream)
{
    const float* y   = (const float*)d_in[0];
    const float* enc = (const float*)d_in[1];
    const float* hid = (const float*)d_in[2];
    // d_in[3] = batch_ids (int32, unused by reference)
    const float* aW  = (const float*)d_in[4];
    const float* ab  = (const float*)d_in[5];
    const float* cW  = (const float*)d_in[6];
    const float* cb  = (const float*)d_in[7];
    const float* wih = (const float*)d_in[8];
    const float* whh = (const float*)d_in[9];
    const float* bih = (const float*)d_in[10];
    const float* bhh = (const float*)d_in[11];
    const float* fW  = (const float*)d_in[12];
    const float* fb  = (const float*)d_in[13];
    float* out = (float*)d_out;

    float4* P = (float4*)d_ws;   // 48*B float4 = 12.58 MB

    precompute_P_kernel<<<4096, 256, 0, stream>>>(enc, cW, P);
    decode_kernel<<<B / 16, 256, 0, stream>>>(
        y, hid, P, aW, ab, cW, cb, wih, whh, bih, bhh, fW, fb, out);
}